// Round 3
// baseline (333.767 us; speedup 1.0000x reference)
//
#include <hip/hip_runtime.h>
#include <hip/hip_bf16.h>

typedef __attribute__((ext_vector_type(8))) short bf16x8;
typedef __attribute__((ext_vector_type(4))) float f32x4;

// ---------------- workspace layout (bytes) ----------------
// 0        : rnorm   f32[8192]
// 64K      : idx_sel i32[8192]
// 96K      : labels_sel i32[8192]
// 128K     : meta    i32[4]  (0: S counter, 2: is64 flag)
// 256K     : fsel    bf16[8192*1024]   (16 MB)
// 256K+16M : sim     f32[Spad*Spad]    (~32 MB for S~2731)

#define OFF_RNORM   0
#define OFF_IDXSEL  (64*1024)
#define OFF_LBLSEL  (96*1024)
#define OFF_META    (128*1024)
#define OFF_FSEL    (256*1024)

__device__ inline unsigned short f2bf(float f){
    union { __hip_bfloat16 h; unsigned short u; } cv;
    cv.h = __float2bfloat16(f);
    return cv.u;
}

// -------- kernel 0: init (zero counter, detect int64 labels) --------
__global__ void init_kernel(const int* __restrict__ labels_raw, int* meta)
{
    if (threadIdx.x == 0) {
        // int64 labels in [0,128): all high words zero. int32 labels: odd
        // entries random in [0,128) -> P(all 128 zero) ~ 0.
        int nz = 0;
        for (int j = 0; j < 128; j++) nz |= labels_raw[2*j + 1];
        meta[2] = (nz == 0) ? 1 : 0;
        meta[0] = 0;
    }
}

// -------- kernel 1: wave-per-row norms + selection + atomic compaction --------
__global__ __launch_bounds__(256) void prep_kernel(
    const float* __restrict__ feats, const float* __restrict__ score,
    const int* __restrict__ type_idx, const void* __restrict__ labels_raw,
    float* __restrict__ rnorm, int* __restrict__ idx_sel,
    int* __restrict__ labels_sel, int* meta, int D)
{
    int row  = blockIdx.x * 4 + (threadIdx.x >> 6);
    int lane = threadIdx.x & 63;
    const float4* fr = (const float4*)(feats + (size_t)row * D);
    float ssq = 0.f;
    int nv = D >> 2;
    for (int i = lane; i < nv; i += 64) {
        float4 v = fr[i];
        ssq += v.x*v.x + v.y*v.y + v.z*v.z + v.w*v.w;
    }
    for (int o = 32; o; o >>= 1) ssq += __shfl_down(ssq, o);
    if (lane == 0) {
        rnorm[row] = 1.0f / fmaxf(sqrtf(ssq), 1e-12f);
        float s0 = score[3*row], s1 = score[3*row+1], s2 = score[3*row+2];
        int am = 0; float b = s0;
        if (s1 > b) { b = s1; am = 1; }
        if (s2 > b) { am = 2; }
        if (am == type_idx[0]) {
            int pos = atomicAdd(&meta[0], 1);
            idx_sel[pos] = row;
            labels_sel[pos] = meta[2] ? (int)((const long long*)labels_raw)[row]
                                      : ((const int*)labels_raw)[row];
        }
    }
}

// -------- kernel 2: wave-per-row gather, normalize, cast bf16 --------
__global__ __launch_bounds__(256) void gather_kernel(
    const float* __restrict__ feats, const float* __restrict__ rnorm,
    const int* __restrict__ idx_sel, const int* __restrict__ meta,
    unsigned short* __restrict__ fsel, int D)
{
    int S = meta[0];
    int Spad = (S + 127) & ~127;
    int s = blockIdx.x * 4 + (threadIdx.x >> 6);
    if (s >= Spad) return;
    int lane = threadIdx.x & 63;
    int nv = D >> 2;
    ushort4* dst = (ushort4*)(fsel + (size_t)s * D);
    if (s < S) {
        int r = idx_sel[s];
        float sc = rnorm[r];
        const float4* src = (const float4*)(feats + (size_t)r * D);
        for (int i = lane; i < nv; i += 64) {
            float4 v = src[i];
            ushort4 o;
            o.x = f2bf(v.x * sc); o.y = f2bf(v.y * sc);
            o.z = f2bf(v.z * sc); o.w = f2bf(v.w * sc);
            dst[i] = o;
        }
    } else {
        ushort4 z = {0,0,0,0};
        for (int i = lane; i < nv; i += 64) dst[i] = z;
    }
}

// -------- kernel 3: sim = fsel * fsel^T (bf16 MFMA, 128x128 tile, BK=64) --------
// kb-major LDS: chunk c in [0,1024): kb=c>>7 (k-octet), r=c&127 (tile row).
// global_load_lds dwordx4: LDS dest = wave-uniform base + lane*16 (layout is
// linear in c, so this matches). Fragment ds_read_b128 conflict-free.
__global__ __launch_bounds__(256) void simgemm_kernel(
    const unsigned short* __restrict__ fsel, const int* __restrict__ meta,
    float* __restrict__ sim, int D)
{
    int S = meta[0];
    int Spad = (S + 127) & ~127;
    int bm = blockIdx.x * 128, bn = blockIdx.y * 128;
    if (bm >= Spad || bn >= Spad) return;

    __shared__ unsigned short lA[1024 * 8];   // 16 KB
    __shared__ unsigned short lB[1024 * 8];   // 16 KB

    int tid = threadIdx.x;
    int lane = tid & 63;
    int wave = tid >> 6;
    int wr = (wave >> 1) * 64;
    int wc = (wave & 1) * 64;
    int laneRow = lane & 15;
    int laneK = lane >> 4;

    f32x4 acc[4][4];
#pragma unroll
    for (int m = 0; m < 4; m++)
#pragma unroll
        for (int n = 0; n < 4; n++)
            acc[m][n] = (f32x4){0.f, 0.f, 0.f, 0.f};

    for (int k0 = 0; k0 < D; k0 += 64) {
        __syncthreads();   // prev iteration's ds_reads done before overwrite
#pragma unroll
        for (int p = 0; p < 4; p++) {
            int c = tid + p * 256;
            int kb = c >> 7, r = c & 127;
            const unsigned short* gA = fsel + (size_t)(bm + r) * D + k0 + kb * 8;
            const unsigned short* gB = fsel + (size_t)(bn + r) * D + k0 + kb * 8;
            __builtin_amdgcn_global_load_lds(
                (const __attribute__((address_space(1))) unsigned int*)gA,
                (__attribute__((address_space(3))) unsigned int*)&lA[c * 8], 16, 0, 0);
            __builtin_amdgcn_global_load_lds(
                (const __attribute__((address_space(1))) unsigned int*)gB,
                (__attribute__((address_space(3))) unsigned int*)&lB[c * 8], 16, 0, 0);
        }
        __syncthreads();   // drains vmcnt

        bf16x8 af[2][4], bfr[2][4];
#pragma unroll
        for (int s = 0; s < 2; s++)
#pragma unroll
            for (int m = 0; m < 4; m++) {
                af[s][m]  = *(const bf16x8*)&lA[((s*4 + laneK)*128 + wr + m*16 + laneRow) * 8];
                bfr[s][m] = *(const bf16x8*)&lB[((s*4 + laneK)*128 + wc + m*16 + laneRow) * 8];
            }
#pragma unroll
        for (int s = 0; s < 2; s++)
#pragma unroll
            for (int m = 0; m < 4; m++)
#pragma unroll
                for (int n = 0; n < 4; n++)
                    acc[m][n] = __builtin_amdgcn_mfma_f32_16x16x32_bf16(
                        af[s][m], bfr[s][n], acc[m][n], 0, 0, 0);
    }

    // C/D layout: col = lane&15, row = (lane>>4)*4 + q
#pragma unroll
    for (int m = 0; m < 4; m++) {
        int row0 = bm + wr + m * 16 + (lane >> 4) * 4;
#pragma unroll
        for (int n = 0; n < 4; n++) {
            int col = bn + wc + n * 16 + laneRow;
#pragma unroll
            for (int q = 0; q < 4; q++)
                sim[(size_t)(row0 + q) * Spad + col] = acc[m][n][q];
        }
    }
}

// -------- kernel 4: wave-per-row loss, atomicAdd scalar --------
__global__ __launch_bounds__(256) void loss_kernel(
    const float* __restrict__ sim, const int* __restrict__ labels_sel,
    const int* __restrict__ meta, float* out, float invB)
{
    int S = meta[0];
    int Spad = (S + 127) & ~127;
    int tid = threadIdx.x;
    __shared__ unsigned char slbl[8192];   // labels < 128 fit a byte
    for (int j = tid; j < S; j += 256) slbl[j] = (unsigned char)labels_sel[j];
    __syncthreads();

    int lane = tid & 63;
    int s = blockIdx.x * 4 + (tid >> 6);   // wave-per-row; grid covers S<=8192
    if (s >= S) return;

    const float* row = sim + (size_t)s * Spad;
    const float ONE_ME = 1.0f - 1e-5f;
    int lbl = slbl[s];

    // pass 1: count, min over positives (<1-eps), max over negatives
    int cnt = 0;
    float minp = INFINITY, maxn = -INFINITY;
    for (int j = lane; j < S; j += 64) {
        float sv = (j == s) ? 1.0f : row[j];
        if (slbl[j] == lbl) {
            cnt++;
            if (sv < ONE_ME) minp = fminf(minp, sv);
        } else {
            maxn = fmaxf(maxn, sv);
        }
    }
    for (int o = 32; o; o >>= 1) {
        cnt += __shfl_down(cnt, o);
        minp = fminf(minp, __shfl_down(minp, o));
        maxn = fmaxf(maxn, __shfl_down(maxn, o));
    }
    cnt  = __shfl(cnt, 0);
    minp = __shfl(minp, 0);
    maxn = __shfl(maxn, 0);

    if (!(cnt > 1 && minp < 3e38f && maxn > -3e38f)) return;

    // pass 2: hard-pair exp sums (row is L2/L3-hot from pass 1)
    float psum = 0.f, nsum = 0.f;
    for (int j = lane; j < S; j += 64) {
        float sv = (j == s) ? 1.0f : row[j];
        if (slbl[j] == lbl) {
            if (sv < ONE_ME && sv - 0.1f < maxn) psum += expf(-2.0f * (sv - 0.5f));
        } else {
            if (sv + 0.1f > minp) nsum += expf(40.0f * (sv - 0.5f));
        }
    }
    for (int o = 32; o; o >>= 1) {
        psum += __shfl_down(psum, o);
        nsum += __shfl_down(nsum, o);
    }
    if (lane == 0 && psum > 0.f && nsum > 0.f) {
        float rl = log1pf(psum) * 0.5f + log1pf(nsum) * 0.025f;
        atomicAdd(out, rl * invB);
    }
}

extern "C" void kernel_launch(void* const* d_in, const int* in_sizes, int n_in,
                              void* d_out, int out_size, void* d_ws, size_t ws_size,
                              hipStream_t stream)
{
    const float* feats    = (const float*)d_in[0];
    const void*  labels   = d_in[1];
    const float* score    = (const float*)d_in[2];
    const int*   type_idx = (const int*)d_in[3];

    int B = in_sizes[1];           // 8192
    int D = in_sizes[0] / B;       // 1024

    char* ws = (char*)d_ws;
    float* rnorm      = (float*)(ws + OFF_RNORM);
    int*   idx_sel    = (int*)  (ws + OFF_IDXSEL);
    int*   labels_sel = (int*)  (ws + OFF_LBLSEL);
    int*   meta       = (int*)  (ws + OFF_META);
    unsigned short* fsel = (unsigned short*)(ws + OFF_FSEL);
    float* sim        = (float*)(ws + OFF_FSEL + (size_t)B * D * 2);
    float* out        = (float*)d_out;

    (void)hipMemsetAsync(d_out, 0, (size_t)out_size * sizeof(float), stream);

    init_kernel<<<1, 64, 0, stream>>>((const int*)labels, meta);
    prep_kernel<<<B / 4, 256, 0, stream>>>(feats, score, type_idx, labels,
                                           rnorm, idx_sel, labels_sel, meta, D);
    gather_kernel<<<B / 4, 256, 0, stream>>>(feats, rnorm, idx_sel, meta, fsel, D);
    dim3 g(B / 128, B / 128);
    simgemm_kernel<<<g, 256, 0, stream>>>(fsel, meta, sim, D);
    loss_kernel<<<B / 4, 256, 0, stream>>>(sim, labels_sel, meta, out, 1.0f / (float)B);
}

// Round 4
// 211.933 us; speedup vs baseline: 1.5749x; 1.5749x over previous
//
#include <hip/hip_runtime.h>
#include <hip/hip_bf16.h>

typedef __attribute__((ext_vector_type(8))) short bf16x8;
typedef __attribute__((ext_vector_type(4))) float f32x4;

// ---------------- workspace layout (bytes) ----------------
// 0        : meta    i32[4]  (0: S counter)
// 64K      : idx_sel i32[8192]
// 96K      : labels_sel i32[8192]
// 256K     : fsel    bf16[8192*1024]   (16 MB)
// 256K+16M : sim     f32[Spad*Spad]    (~32 MB for S~2731)

#define OFF_META    0
#define OFF_IDXSEL  (64*1024)
#define OFF_LBLSEL  (96*1024)
#define OFF_FSEL    (256*1024)

__device__ inline unsigned short f2bf(float f){
    union { __hip_bfloat16 h; unsigned short u; } cv;
    cv.h = __float2bfloat16(f);
    return cv.u;
}

// -------- kernel 1: selection + compaction (1 atomic per block) --------
__global__ __launch_bounds__(256) void select_kernel(
    const float* __restrict__ score, const int* __restrict__ type_idx,
    const void* __restrict__ labels_raw,
    int* __restrict__ idx_sel, int* __restrict__ labels_sel,
    int* meta, int B)
{
    int tid = threadIdx.x, lane = tid & 63, wid = tid >> 6;
    int row = blockIdx.x * 256 + tid;
    __shared__ int s_is64, s_wcnt[4], s_base;

    // int64 vs int32 label detection (per-block, identical answer everywhere):
    // int64 labels in [0,128) have all-zero high words; int32 random labels
    // at odd indices are ~never all zero across 64 samples.
    if (wid == 0) {
        int hi = ((const int*)labels_raw)[2 * lane + 1];
        unsigned long long nz = __ballot(hi != 0);
        if (lane == 0) s_is64 = (nz == 0ULL) ? 1 : 0;
    }

    int f = 0;
    if (row < B) {
        float s0 = score[3*row], s1 = score[3*row+1], s2 = score[3*row+2];
        int am = 0; float b = s0;
        if (s1 > b) { b = s1; am = 1; }
        if (s2 > b) { am = 2; }
        f = (am == type_idx[0]) ? 1 : 0;
    }
    unsigned long long m = __ballot(f != 0);
    int incl = __popcll(m & ((2ULL << lane) - 1ULL));   // inclusive prefix
    if (lane == 0) s_wcnt[wid] = __popcll(m);
    __syncthreads();
    if (tid == 0)
        s_base = atomicAdd(&meta[0], s_wcnt[0] + s_wcnt[1] + s_wcnt[2] + s_wcnt[3]);
    __syncthreads();
    if (f) {
        int prefix = 0;
        for (int w = 0; w < wid; w++) prefix += s_wcnt[w];
        int pos = s_base + prefix + incl - 1;
        idx_sel[pos] = row;
        labels_sel[pos] = s_is64 ? (int)((const long long*)labels_raw)[row]
                                 : ((const int*)labels_raw)[row];
    }
}

// -------- kernel 2: fused normalize+gather of selected rows only --------
// Wave-per-row; row held in registers between ssq reduce and bf16 store.
__global__ __launch_bounds__(256) void gather_kernel(
    const float* __restrict__ feats, const int* __restrict__ idx_sel,
    const int* __restrict__ meta, unsigned short* __restrict__ fsel, int D)
{
    int S = meta[0];
    int Spad = (S + 127) & ~127;
    int s = blockIdx.x * 4 + (threadIdx.x >> 6);
    if (s >= Spad) return;
    int lane = threadIdx.x & 63;
    ushort4* dst = (ushort4*)(fsel + (size_t)s * D);

    if (s >= S) {   // zero padding rows
        ushort4 z = {0,0,0,0};
        for (int i = lane; i < (D >> 2); i += 64) dst[i] = z;
        return;
    }

    int r = idx_sel[s];
    const float4* src = (const float4*)(feats + (size_t)r * D);

    if (D == 1024) {   // fast path: 4 float4 per lane, full ILP
        float4 v[4];
#pragma unroll
        for (int i = 0; i < 4; i++) v[i] = src[lane + i * 64];
        float ssq = 0.f;
#pragma unroll
        for (int i = 0; i < 4; i++)
            ssq += v[i].x*v[i].x + v[i].y*v[i].y + v[i].z*v[i].z + v[i].w*v[i].w;
        for (int o = 32; o; o >>= 1) ssq += __shfl_down(ssq, o);
        ssq = __shfl(ssq, 0);
        float sc = 1.0f / fmaxf(sqrtf(ssq), 1e-12f);
#pragma unroll
        for (int i = 0; i < 4; i++) {
            ushort4 o;
            o.x = f2bf(v[i].x * sc); o.y = f2bf(v[i].y * sc);
            o.z = f2bf(v[i].z * sc); o.w = f2bf(v[i].w * sc);
            dst[lane + i * 64] = o;
        }
    } else {           // generic fallback
        int nv = D >> 2;
        float ssq = 0.f;
        for (int i = lane; i < nv; i += 64) {
            float4 v = src[i];
            ssq += v.x*v.x + v.y*v.y + v.z*v.z + v.w*v.w;
        }
        for (int o = 32; o; o >>= 1) ssq += __shfl_down(ssq, o);
        ssq = __shfl(ssq, 0);
        float sc = 1.0f / fmaxf(sqrtf(ssq), 1e-12f);
        for (int i = lane; i < nv; i += 64) {
            float4 v = src[i];
            ushort4 o;
            o.x = f2bf(v.x * sc); o.y = f2bf(v.y * sc);
            o.z = f2bf(v.z * sc); o.w = f2bf(v.w * sc);
            dst[i] = o;
        }
    }
}

// -------- kernel 3: sim = fsel * fsel^T (bf16 MFMA, 128x128 tile, BK=64) --------
// kb-major LDS: chunk c in [0,1024): kb=c>>7 (k-octet), r=c&127 (tile row).
// global_load_lds dwordx4: linear LDS dest matches wave-uniform base + lane*16.
__global__ __launch_bounds__(256) void simgemm_kernel(
    const unsigned short* __restrict__ fsel, const int* __restrict__ meta,
    float* __restrict__ sim, int D)
{
    int S = meta[0];
    int Spad = (S + 127) & ~127;
    int bm = blockIdx.x * 128, bn = blockIdx.y * 128;
    if (bm >= Spad || bn >= Spad) return;

    __shared__ unsigned short lA[1024 * 8];   // 16 KB
    __shared__ unsigned short lB[1024 * 8];   // 16 KB

    int tid = threadIdx.x;
    int lane = tid & 63;
    int wave = tid >> 6;
    int wr = (wave >> 1) * 64;
    int wc = (wave & 1) * 64;
    int laneRow = lane & 15;
    int laneK = lane >> 4;

    f32x4 acc[4][4];
#pragma unroll
    for (int m = 0; m < 4; m++)
#pragma unroll
        for (int n = 0; n < 4; n++)
            acc[m][n] = (f32x4){0.f, 0.f, 0.f, 0.f};

    for (int k0 = 0; k0 < D; k0 += 64) {
        __syncthreads();
#pragma unroll
        for (int p = 0; p < 4; p++) {
            int c = tid + p * 256;
            int kb = c >> 7, r = c & 127;
            const unsigned short* gA = fsel + (size_t)(bm + r) * D + k0 + kb * 8;
            const unsigned short* gB = fsel + (size_t)(bn + r) * D + k0 + kb * 8;
            __builtin_amdgcn_global_load_lds(
                (const __attribute__((address_space(1))) unsigned int*)gA,
                (__attribute__((address_space(3))) unsigned int*)&lA[c * 8], 16, 0, 0);
            __builtin_amdgcn_global_load_lds(
                (const __attribute__((address_space(1))) unsigned int*)gB,
                (__attribute__((address_space(3))) unsigned int*)&lB[c * 8], 16, 0, 0);
        }
        __syncthreads();

        bf16x8 af[2][4], bfr[2][4];
#pragma unroll
        for (int s2 = 0; s2 < 2; s2++)
#pragma unroll
            for (int m = 0; m < 4; m++) {
                af[s2][m]  = *(const bf16x8*)&lA[((s2*4 + laneK)*128 + wr + m*16 + laneRow) * 8];
                bfr[s2][m] = *(const bf16x8*)&lB[((s2*4 + laneK)*128 + wc + m*16 + laneRow) * 8];
            }
#pragma unroll
        for (int s2 = 0; s2 < 2; s2++)
#pragma unroll
            for (int m = 0; m < 4; m++)
#pragma unroll
                for (int n = 0; n < 4; n++)
                    acc[m][n] = __builtin_amdgcn_mfma_f32_16x16x32_bf16(
                        af[s2][m], bfr[s2][n], acc[m][n], 0, 0, 0);
    }

    // C/D layout: col = lane&15, row = (lane>>4)*4 + q
#pragma unroll
    for (int m = 0; m < 4; m++) {
        int row0 = bm + wr + m * 16 + (lane >> 4) * 4;
#pragma unroll
        for (int n = 0; n < 4; n++) {
            int col = bn + wc + n * 16 + laneRow;
#pragma unroll
            for (int q = 0; q < 4; q++)
                sim[(size_t)(row0 + q) * Spad + col] = acc[m][n][q];
        }
    }
}

// -------- kernel 4: wave-per-row loss, atomicAdd scalar --------
__global__ __launch_bounds__(256) void loss_kernel(
    const float* __restrict__ sim, const int* __restrict__ labels_sel,
    const int* __restrict__ meta, float* out, float invB)
{
    int S = meta[0];
    if (blockIdx.x * 4 >= S) return;     // whole block beyond valid rows
    int Spad = (S + 127) & ~127;
    int tid = threadIdx.x;
    __shared__ unsigned char slbl[8192];   // labels < 128 fit a byte
    for (int j = tid; j < S; j += 256) slbl[j] = (unsigned char)labels_sel[j];
    __syncthreads();

    int lane = tid & 63;
    int s = blockIdx.x * 4 + (tid >> 6);
    if (s >= S) return;

    const float* row = sim + (size_t)s * Spad;
    const float ONE_ME = 1.0f - 1e-5f;
    int lbl = slbl[s];

    // pass 1: count, min over positives (<1-eps), max over negatives
    int cnt = 0;
    float minp = INFINITY, maxn = -INFINITY;
    for (int j = lane; j < S; j += 64) {
        float sv = (j == s) ? 1.0f : row[j];
        if (slbl[j] == lbl) {
            cnt++;
            if (sv < ONE_ME) minp = fminf(minp, sv);
        } else {
            maxn = fmaxf(maxn, sv);
        }
    }
    for (int o = 32; o; o >>= 1) {
        cnt += __shfl_down(cnt, o);
        minp = fminf(minp, __shfl_down(minp, o));
        maxn = fmaxf(maxn, __shfl_down(maxn, o));
    }
    cnt  = __shfl(cnt, 0);
    minp = __shfl(minp, 0);
    maxn = __shfl(maxn, 0);

    if (!(cnt > 1 && minp < 3e38f && maxn > -3e38f)) return;

    // pass 2: hard-pair exp sums (row L2/L3-hot from pass 1)
    float psum = 0.f, nsum = 0.f;
    for (int j = lane; j < S; j += 64) {
        float sv = (j == s) ? 1.0f : row[j];
        if (slbl[j] == lbl) {
            if (sv < ONE_ME && sv - 0.1f < maxn) psum += expf(-2.0f * (sv - 0.5f));
        } else {
            if (sv + 0.1f > minp) nsum += expf(40.0f * (sv - 0.5f));
        }
    }
    for (int o = 32; o; o >>= 1) {
        psum += __shfl_down(psum, o);
        nsum += __shfl_down(nsum, o);
    }
    if (lane == 0 && psum > 0.f && nsum > 0.f) {
        float rl = log1pf(psum) * 0.5f + log1pf(nsum) * 0.025f;
        atomicAdd(out, rl * invB);
    }
}

extern "C" void kernel_launch(void* const* d_in, const int* in_sizes, int n_in,
                              void* d_out, int out_size, void* d_ws, size_t ws_size,
                              hipStream_t stream)
{
    const float* feats    = (const float*)d_in[0];
    const void*  labels   = d_in[1];
    const float* score    = (const float*)d_in[2];
    const int*   type_idx = (const int*)d_in[3];

    int B = in_sizes[1];           // 8192
    int D = in_sizes[0] / B;       // 1024

    char* ws = (char*)d_ws;
    int*   meta       = (int*)  (ws + OFF_META);
    int*   idx_sel    = (int*)  (ws + OFF_IDXSEL);
    int*   labels_sel = (int*)  (ws + OFF_LBLSEL);
    unsigned short* fsel = (unsigned short*)(ws + OFF_FSEL);
    float* sim        = (float*)(ws + OFF_FSEL + (size_t)B * D * 2);
    float* out        = (float*)d_out;

    (void)hipMemsetAsync(d_out, 0, (size_t)out_size * sizeof(float), stream);
    (void)hipMemsetAsync(meta, 0, 16, stream);

    select_kernel<<<(B + 255) / 256, 256, 0, stream>>>(score, type_idx, labels,
                                                       idx_sel, labels_sel, meta, B);
    gather_kernel<<<B / 4, 256, 0, stream>>>(feats, idx_sel, meta, fsel, D);
    dim3 g(B / 128, B / 128);
    simgemm_kernel<<<g, 256, 0, stream>>>(fsel, meta, sim, D);
    loss_kernel<<<B / 4, 256, 0, stream>>>(sim, labels_sel, meta, out, 1.0f / (float)B);
}

// Round 6
// 185.317 us; speedup vs baseline: 1.8011x; 1.1436x over previous
//
#include <hip/hip_runtime.h>
#include <hip/hip_bf16.h>

typedef __attribute__((ext_vector_type(8))) short bf16x8;
typedef __attribute__((ext_vector_type(4))) float f32x4;

// ---------------- workspace layout (bytes) ----------------
// 0        : meta    i32[4]  (0: S counter)
// 64K      : idx_sel i32[8192]
// 96K      : labels_sel i32[8192]
// 160K     : row_loss f32[8192]
// 256K     : fsel    bf16[8192*1024]   (16 MB)
// 256K+16M : sim     f32[Spad*Spad]    (~32 MB for S~2731)

#define OFF_META    0
#define OFF_IDXSEL  (64*1024)
#define OFF_LBLSEL  (96*1024)
#define OFF_RLOSS   (160*1024)
#define OFF_FSEL    (256*1024)

__device__ inline unsigned short f2bf(float f){
    union { __hip_bfloat16 h; unsigned short u; } cv;
    cv.h = __float2bfloat16(f);
    return cv.u;
}

// -------- kernel 1: selection + compaction (1 atomic per block, 32 blocks) --------
__global__ __launch_bounds__(256) void select_kernel(
    const float* __restrict__ score, const int* __restrict__ type_idx,
    const void* __restrict__ labels_raw,
    int* __restrict__ idx_sel, int* __restrict__ labels_sel,
    int* meta, int B)
{
    int tid = threadIdx.x, lane = tid & 63, wid = tid >> 6;
    int row = blockIdx.x * 256 + tid;
    __shared__ int s_is64, s_wcnt[4], s_base;

    // int64 vs int32 label detection: int64 labels in [0,128) have all-zero
    // high words; int32 random labels at odd indices ~never all zero.
    if (wid == 0) {
        int hi = ((const int*)labels_raw)[2 * lane + 1];
        unsigned long long nz = __ballot(hi != 0);
        if (lane == 0) s_is64 = (nz == 0ULL) ? 1 : 0;
    }

    int f = 0;
    if (row < B) {
        float s0 = score[3*row], s1 = score[3*row+1], s2 = score[3*row+2];
        int am = 0; float b = s0;
        if (s1 > b) { b = s1; am = 1; }
        if (s2 > b) { am = 2; }
        f = (am == type_idx[0]) ? 1 : 0;
    }
    unsigned long long m = __ballot(f != 0);
    int incl = __popcll(m & ((2ULL << lane) - 1ULL));
    if (lane == 0) s_wcnt[wid] = __popcll(m);
    __syncthreads();
    if (tid == 0)
        s_base = atomicAdd(&meta[0], s_wcnt[0] + s_wcnt[1] + s_wcnt[2] + s_wcnt[3]);
    __syncthreads();
    if (f) {
        int prefix = 0;
        for (int w = 0; w < wid; w++) prefix += s_wcnt[w];
        int pos = s_base + prefix + incl - 1;
        idx_sel[pos] = row;
        labels_sel[pos] = s_is64 ? (int)((const long long*)labels_raw)[row]
                                 : ((const int*)labels_raw)[row];
    }
}

// -------- kernel 2: fused normalize+gather of selected rows only --------
__global__ __launch_bounds__(256) void gather_kernel(
    const float* __restrict__ feats, const int* __restrict__ idx_sel,
    const int* __restrict__ meta, unsigned short* __restrict__ fsel, int D)
{
    int S = meta[0];
    int Spad = (S + 127) & ~127;
    int s = blockIdx.x * 4 + (threadIdx.x >> 6);
    if (s >= Spad) return;
    int lane = threadIdx.x & 63;
    ushort4* dst = (ushort4*)(fsel + (size_t)s * D);

    if (s >= S) {   // zero padding rows
        ushort4 z = {0,0,0,0};
        for (int i = lane; i < (D >> 2); i += 64) dst[i] = z;
        return;
    }

    int r = idx_sel[s];
    const float4* src = (const float4*)(feats + (size_t)r * D);

    if (D == 1024) {
        float4 v[4];
#pragma unroll
        for (int i = 0; i < 4; i++) v[i] = src[lane + i * 64];
        float ssq = 0.f;
#pragma unroll
        for (int i = 0; i < 4; i++)
            ssq += v[i].x*v[i].x + v[i].y*v[i].y + v[i].z*v[i].z + v[i].w*v[i].w;
        for (int o = 32; o; o >>= 1) ssq += __shfl_down(ssq, o);
        ssq = __shfl(ssq, 0);
        float sc = 1.0f / fmaxf(sqrtf(ssq), 1e-12f);
#pragma unroll
        for (int i = 0; i < 4; i++) {
            ushort4 o;
            o.x = f2bf(v[i].x * sc); o.y = f2bf(v[i].y * sc);
            o.z = f2bf(v[i].z * sc); o.w = f2bf(v[i].w * sc);
            dst[lane + i * 64] = o;
        }
    } else {
        int nv = D >> 2;
        float ssq = 0.f;
        for (int i = lane; i < nv; i += 64) {
            float4 v = src[i];
            ssq += v.x*v.x + v.y*v.y + v.z*v.z + v.w*v.w;
        }
        for (int o = 32; o; o >>= 1) ssq += __shfl_down(ssq, o);
        ssq = __shfl(ssq, 0);
        float sc = 1.0f / fmaxf(sqrtf(ssq), 1e-12f);
        for (int i = lane; i < nv; i += 64) {
            float4 v = src[i];
            ushort4 o;
            o.x = f2bf(v.x * sc); o.y = f2bf(v.y * sc);
            o.z = f2bf(v.z * sc); o.w = f2bf(v.w * sc);
            dst[i] = o;
        }
    }
}

// -------- kernel 3: sim = fsel * fsel^T --------
// 128x128 tile, BK=64, double-buffered LDS, counted vmcnt (T3/T4 2-phase):
// loads for tile t+1 stay in flight across the barrier while tile t computes.
__global__ __launch_bounds__(256) void simgemm_kernel(
    const unsigned short* __restrict__ fsel, const int* __restrict__ meta,
    float* __restrict__ sim, int D)
{
    int S = meta[0];
    int Spad = (S + 127) & ~127;
    int bm = blockIdx.x * 128, bn = blockIdx.y * 128;
    if (bm >= Spad || bn >= Spad) return;

    __shared__ unsigned short lA[2][1024 * 8];   // 2 x 16 KB
    __shared__ unsigned short lB[2][1024 * 8];   // 2 x 16 KB

    int tid = threadIdx.x;
    int lane = tid & 63;
    int wave = tid >> 6;
    int wr = (wave >> 1) * 64;
    int wc = (wave & 1) * 64;
    int laneRow = lane & 15;
    int laneK = lane >> 4;

    f32x4 acc[4][4];
#pragma unroll
    for (int m = 0; m < 4; m++)
#pragma unroll
        for (int n = 0; n < 4; n++)
            acc[m][n] = (f32x4){0.f, 0.f, 0.f, 0.f};

    // stage one K-tile (8 global_load_lds_dwordx4 per thread)
#define STAGE(buf, k0)                                                        \
    _Pragma("unroll")                                                         \
    for (int p = 0; p < 4; p++) {                                             \
        int c = tid + p * 256;                                                \
        int kb = c >> 7, r = c & 127;                                         \
        __builtin_amdgcn_global_load_lds(                                     \
            (const __attribute__((address_space(1))) unsigned int*)           \
                (fsel + (size_t)(bm + r) * D + (k0) + kb * 8),                \
            (__attribute__((address_space(3))) unsigned int*)&lA[buf][c * 8], \
            16, 0, 0);                                                        \
        __builtin_amdgcn_global_load_lds(                                     \
            (const __attribute__((address_space(1))) unsigned int*)           \
                (fsel + (size_t)(bn + r) * D + (k0) + kb * 8),                \
            (__attribute__((address_space(3))) unsigned int*)&lB[buf][c * 8], \
            16, 0, 0);                                                        \
    }

    int nt = D >> 6;
    STAGE(0, 0)
    int cur = 0;
    for (int t = 0; t < nt; t++) {
        if (t + 1 < nt) {
            STAGE(cur ^ 1, (t + 1) << 6)
            asm volatile("s_waitcnt vmcnt(8)" ::: "memory");  // cur's 8 landed
        } else {
            asm volatile("s_waitcnt vmcnt(0)" ::: "memory");
        }
        __builtin_amdgcn_s_barrier();
        __builtin_amdgcn_sched_barrier(0);   // keep ds_reads after the barrier

        bf16x8 af[2][4], bfr[2][4];
#pragma unroll
        for (int s2 = 0; s2 < 2; s2++)
#pragma unroll
            for (int m = 0; m < 4; m++) {
                af[s2][m]  = *(const bf16x8*)&lA[cur][((s2*4 + laneK)*128 + wr + m*16 + laneRow) * 8];
                bfr[s2][m] = *(const bf16x8*)&lB[cur][((s2*4 + laneK)*128 + wc + m*16 + laneRow) * 8];
            }
#pragma unroll
        for (int s2 = 0; s2 < 2; s2++)
#pragma unroll
            for (int m = 0; m < 4; m++)
#pragma unroll
                for (int n = 0; n < 4; n++)
                    acc[m][n] = __builtin_amdgcn_mfma_f32_16x16x32_bf16(
                        af[s2][m], bfr[s2][n], acc[m][n], 0, 0, 0);

        __builtin_amdgcn_sched_barrier(0);   // ds_reads consumed before barrier
        __builtin_amdgcn_s_barrier();        // safe to overwrite buf[cur] next iter
        cur ^= 1;
    }
#undef STAGE

    // C/D layout: col = lane&15, row = (lane>>4)*4 + q
#pragma unroll
    for (int m = 0; m < 4; m++) {
        int row0 = bm + wr + m * 16 + (lane >> 4) * 4;
#pragma unroll
        for (int n = 0; n < 4; n++) {
            int col = bn + wc + n * 16 + laneRow;
#pragma unroll
            for (int q = 0; q < 4; q++)
                sim[(size_t)(row0 + q) * Spad + col] = acc[m][n][q];
        }
    }
}

// -------- kernel 4: wave-per-row loss -> row_loss[s] (no atomics) --------
__global__ __launch_bounds__(256) void loss_kernel(
    const float* __restrict__ sim, const int* __restrict__ labels_sel,
    const int* __restrict__ meta, float* __restrict__ row_loss)
{
    int S = meta[0];
    if (blockIdx.x * 4 >= S) return;
    int Spad = (S + 127) & ~127;
    int tid = threadIdx.x;
    __shared__ unsigned char slbl[8192];   // labels < 128 fit a byte
    for (int j = tid; j < S; j += 256) slbl[j] = (unsigned char)labels_sel[j];
    __syncthreads();

    int lane = tid & 63;
    int s = blockIdx.x * 4 + (tid >> 6);
    if (s >= S) return;

    const float* row = sim + (size_t)s * Spad;
    const float ONE_ME = 1.0f - 1e-5f;
    int lbl = slbl[s];

    // pass 1: count, min over positives (<1-eps), max over negatives
    int cnt = 0;
    float minp = INFINITY, maxn = -INFINITY;
    for (int j = lane; j < S; j += 64) {
        float sv = (j == s) ? 1.0f : row[j];
        if (slbl[j] == lbl) {
            cnt++;
            if (sv < ONE_ME) minp = fminf(minp, sv);
        } else {
            maxn = fmaxf(maxn, sv);
        }
    }
    for (int o = 32; o; o >>= 1) {
        cnt += __shfl_down(cnt, o);
        minp = fminf(minp, __shfl_down(minp, o));
        maxn = fmaxf(maxn, __shfl_down(maxn, o));
    }
    cnt  = __shfl(cnt, 0);
    minp = __shfl(minp, 0);
    maxn = __shfl(maxn, 0);

    float rl = 0.f;
    if (cnt > 1 && minp < 3e38f && maxn > -3e38f) {
        // pass 2: hard-pair exp sums (row L2/L3-hot from pass 1)
        float psum = 0.f, nsum = 0.f;
        for (int j = lane; j < S; j += 64) {
            float sv = (j == s) ? 1.0f : row[j];
            if (slbl[j] == lbl) {
                if (sv < ONE_ME && sv - 0.1f < maxn) psum += expf(-2.0f * (sv - 0.5f));
            } else {
                if (sv + 0.1f > minp) nsum += expf(40.0f * (sv - 0.5f));
            }
        }
        for (int o = 32; o; o >>= 1) {
            psum += __shfl_down(psum, o);
            nsum += __shfl_down(nsum, o);
        }
        if (psum > 0.f && nsum > 0.f)
            rl = log1pf(psum) * 0.5f + log1pf(nsum) * 0.025f;
    }
    if (lane == 0) row_loss[s] = rl;
}

// -------- kernel 5: final reduction of row_loss --------
__global__ __launch_bounds__(256) void reduce_kernel(
    const float* __restrict__ row_loss, const int* __restrict__ meta,
    float* out, float invB)
{
    int S = meta[0];
    float sum = 0.f;
    for (int j = threadIdx.x; j < S; j += 256) sum += row_loss[j];
    for (int o = 32; o; o >>= 1) sum += __shfl_down(sum, o);
    __shared__ float sm[4];
    if ((threadIdx.x & 63) == 0) sm[threadIdx.x >> 6] = sum;
    __syncthreads();
    if (threadIdx.x == 0) out[0] = (sm[0] + sm[1] + sm[2] + sm[3]) * invB;
}

extern "C" void kernel_launch(void* const* d_in, const int* in_sizes, int n_in,
                              void* d_out, int out_size, void* d_ws, size_t ws_size,
                              hipStream_t stream)
{
    const float* feats    = (const float*)d_in[0];
    const void*  labels   = d_in[1];
    const float* score    = (const float*)d_in[2];
    const int*   type_idx = (const int*)d_in[3];

    int B = in_sizes[1];           // 8192
    int D = in_sizes[0] / B;       // 1024

    char* ws = (char*)d_ws;
    int*   meta       = (int*)  (ws + OFF_META);
    int*   idx_sel    = (int*)  (ws + OFF_IDXSEL);
    int*   labels_sel = (int*)  (ws + OFF_LBLSEL);
    float* row_loss   = (float*)(ws + OFF_RLOSS);
    unsigned short* fsel = (unsigned short*)(ws + OFF_FSEL);
    float* sim        = (float*)(ws + OFF_FSEL + (size_t)B * D * 2);
    float* out        = (float*)d_out;

    (void)hipMemsetAsync(meta, 0, 16, stream);

    select_kernel<<<(B + 255) / 256, 256, 0, stream>>>(score, type_idx, labels,
                                                       idx_sel, labels_sel, meta, B);
    gather_kernel<<<B / 4, 256, 0, stream>>>(feats, idx_sel, meta, fsel, D);
    dim3 g(B / 128, B / 128);
    simgemm_kernel<<<g, 256, 0, stream>>>(fsel, meta, sim, D);
    loss_kernel<<<B / 4, 256, 0, stream>>>(sim, labels_sel, meta, row_loss);
    reduce_kernel<<<1, 256, 0, stream>>>(row_loss, meta, out, 1.0f / (float)B);
}

// Round 7
// 138.835 us; speedup vs baseline: 2.4041x; 1.3348x over previous
//
#include <hip/hip_runtime.h>
#include <hip/hip_bf16.h>

typedef __attribute__((ext_vector_type(8))) short bf16x8;
typedef __attribute__((ext_vector_type(4))) float f32x4;

// ---------------- workspace layout (bytes) ----------------
// 0        : meta    i32[4]  (0: S counter)
// 64K      : idx_sel i32[8192]
// 96K      : labels_sel i32[8192]
// 160K     : row_loss f32[8192]
// 256K     : fsel    bf16[8192*1024]   (16 MB)
// 256K+16M : sim     f32[Spad*Spad]    (~32 MB for S~2731)

#define OFF_META    0
#define OFF_IDXSEL  (64*1024)
#define OFF_LBLSEL  (96*1024)
#define OFF_RLOSS   (160*1024)
#define OFF_FSEL    (256*1024)

__device__ inline unsigned short f2bf(float f){
    union { __hip_bfloat16 h; unsigned short u; } cv;
    cv.h = __float2bfloat16(f);
    return cv.u;
}

// -------- kernel 1: selection + compaction (1 atomic per block, 32 blocks) --------
__global__ __launch_bounds__(256) void select_kernel(
    const float* __restrict__ score, const int* __restrict__ type_idx,
    const void* __restrict__ labels_raw,
    int* __restrict__ idx_sel, int* __restrict__ labels_sel,
    int* meta, int B)
{
    int tid = threadIdx.x, lane = tid & 63, wid = tid >> 6;
    int row = blockIdx.x * 256 + tid;
    __shared__ int s_is64, s_wcnt[4], s_base;

    // int64 vs int32 label detection: int64 labels in [0,128) have all-zero
    // high words; int32 random labels at odd indices ~never all zero.
    if (wid == 0) {
        int hi = ((const int*)labels_raw)[2 * lane + 1];
        unsigned long long nz = __ballot(hi != 0);
        if (lane == 0) s_is64 = (nz == 0ULL) ? 1 : 0;
    }

    int f = 0;
    if (row < B) {
        float s0 = score[3*row], s1 = score[3*row+1], s2 = score[3*row+2];
        int am = 0; float b = s0;
        if (s1 > b) { b = s1; am = 1; }
        if (s2 > b) { am = 2; }
        f = (am == type_idx[0]) ? 1 : 0;
    }
    unsigned long long m = __ballot(f != 0);
    int incl = __popcll(m & ((2ULL << lane) - 1ULL));
    if (lane == 0) s_wcnt[wid] = __popcll(m);
    __syncthreads();
    if (tid == 0)
        s_base = atomicAdd(&meta[0], s_wcnt[0] + s_wcnt[1] + s_wcnt[2] + s_wcnt[3]);
    __syncthreads();
    if (f) {
        int prefix = 0;
        for (int w = 0; w < wid; w++) prefix += s_wcnt[w];
        int pos = s_base + prefix + incl - 1;
        idx_sel[pos] = row;
        labels_sel[pos] = s_is64 ? (int)((const long long*)labels_raw)[row]
                                 : ((const int*)labels_raw)[row];
    }
}

// -------- kernel 2: fused normalize+gather of selected rows only --------
__global__ __launch_bounds__(256) void gather_kernel(
    const float* __restrict__ feats, const int* __restrict__ idx_sel,
    const int* __restrict__ meta, unsigned short* __restrict__ fsel, int D)
{
    int S = meta[0];
    int Spad = (S + 127) & ~127;
    int s = blockIdx.x * 4 + (threadIdx.x >> 6);
    if (s >= Spad) return;
    int lane = threadIdx.x & 63;
    ushort4* dst = (ushort4*)(fsel + (size_t)s * D);

    if (s >= S) {   // zero padding rows
        ushort4 z = {0,0,0,0};
        for (int i = lane; i < (D >> 2); i += 64) dst[i] = z;
        return;
    }

    int r = idx_sel[s];
    const float4* src = (const float4*)(feats + (size_t)r * D);

    if (D == 1024) {
        float4 v[4];
#pragma unroll
        for (int i = 0; i < 4; i++) v[i] = src[lane + i * 64];
        float ssq = 0.f;
#pragma unroll
        for (int i = 0; i < 4; i++)
            ssq += v[i].x*v[i].x + v[i].y*v[i].y + v[i].z*v[i].z + v[i].w*v[i].w;
        for (int o = 32; o; o >>= 1) ssq += __shfl_down(ssq, o);
        ssq = __shfl(ssq, 0);
        float sc = 1.0f / fmaxf(sqrtf(ssq), 1e-12f);
#pragma unroll
        for (int i = 0; i < 4; i++) {
            ushort4 o;
            o.x = f2bf(v[i].x * sc); o.y = f2bf(v[i].y * sc);
            o.z = f2bf(v[i].z * sc); o.w = f2bf(v[i].w * sc);
            dst[lane + i * 64] = o;
        }
    } else {
        int nv = D >> 2;
        float ssq = 0.f;
        for (int i = lane; i < nv; i += 64) {
            float4 v = src[i];
            ssq += v.x*v.x + v.y*v.y + v.z*v.z + v.w*v.w;
        }
        for (int o = 32; o; o >>= 1) ssq += __shfl_down(ssq, o);
        ssq = __shfl(ssq, 0);
        float sc = 1.0f / fmaxf(sqrtf(ssq), 1e-12f);
        for (int i = lane; i < nv; i += 64) {
            float4 v = src[i];
            ushort4 o;
            o.x = f2bf(v.x * sc); o.y = f2bf(v.y * sc);
            o.z = f2bf(v.z * sc); o.w = f2bf(v.w * sc);
            dst[i] = o;
        }
    }
}

// -------- kernel 3: sim = fsel * fsel^T --------
// 128x128 tile, 8 waves (512 thr), BK=64, double-buffered LDS, counted vmcnt.
// LDS layout: row-major [128 rows][8 slots][16B] where octet o of row r lives
// at slot (o ^ (r&7))  — XOR-swizzle applied on the GLOBAL source address
// (global_load_lds dest must stay linear: base + lane*16), and re-applied on
// the ds_read side. Staging lanes read contiguous 128B row-chunks (coalesced);
// frag reads spread across banks via the XOR.
__global__ __launch_bounds__(512) void simgemm_kernel(
    const unsigned short* __restrict__ fsel, const int* __restrict__ meta,
    float* __restrict__ sim, int D)
{
    int S = meta[0];
    int Spad = (S + 127) & ~127;
    int bm = blockIdx.x * 128, bn = blockIdx.y * 128;
    if (bm >= Spad || bn >= Spad) return;

    __shared__ unsigned short lA[2][1024 * 8];   // 2 x 16 KB
    __shared__ unsigned short lB[2][1024 * 8];   // 2 x 16 KB

    int tid = threadIdx.x;
    int lane = tid & 63;
    int wave = tid >> 6;
    int wr = (wave >> 2) * 64;   // 2 wave-rows
    int wc = (wave & 3) * 32;    // 4 wave-cols
    int laneRow = lane & 15;
    int laneK = lane >> 4;

    f32x4 acc[4][2];
#pragma unroll
    for (int m = 0; m < 4; m++)
#pragma unroll
        for (int n = 0; n < 2; n++)
            acc[m][n] = (f32x4){0.f, 0.f, 0.f, 0.f};

    // stage one K-tile: 4 global_load_lds_dwordx4 per thread (2 A + 2 B)
#define STAGE(buf, k0)                                                        \
    _Pragma("unroll")                                                         \
    for (int p = 0; p < 2; p++) {                                             \
        int c = tid + p * 512;                                                \
        int r = c >> 3, slot = c & 7;                                         \
        int og = slot ^ (r & 7);                                              \
        __builtin_amdgcn_global_load_lds(                                     \
            (const __attribute__((address_space(1))) unsigned int*)           \
                (fsel + (size_t)(bm + r) * D + (k0) + og * 8),                \
            (__attribute__((address_space(3))) unsigned int*)&lA[buf][c * 8], \
            16, 0, 0);                                                        \
        __builtin_amdgcn_global_load_lds(                                     \
            (const __attribute__((address_space(1))) unsigned int*)           \
                (fsel + (size_t)(bn + r) * D + (k0) + og * 8),                \
            (__attribute__((address_space(3))) unsigned int*)&lB[buf][c * 8], \
            16, 0, 0);                                                        \
    }

    int nt = D >> 6;
    STAGE(0, 0)
    int cur = 0;
    for (int t = 0; t < nt; t++) {
        if (t + 1 < nt) {
            STAGE(cur ^ 1, (t + 1) << 6)
            asm volatile("s_waitcnt vmcnt(4)" ::: "memory");  // cur's 4 landed
        } else {
            asm volatile("s_waitcnt vmcnt(0)" ::: "memory");
        }
        __builtin_amdgcn_s_barrier();
        __builtin_amdgcn_sched_barrier(0);   // keep ds_reads after the barrier

        bf16x8 af[2][4], bfr[2][2];
#pragma unroll
        for (int s2 = 0; s2 < 2; s2++) {
            int o = s2 * 4 + laneK;
#pragma unroll
            for (int m = 0; m < 4; m++) {
                int row = wr + m * 16 + laneRow;
                af[s2][m] = *(const bf16x8*)&lA[cur][(row * 8 + (o ^ (row & 7))) * 8];
            }
#pragma unroll
            for (int n = 0; n < 2; n++) {
                int row = wc + n * 16 + laneRow;
                bfr[s2][n] = *(const bf16x8*)&lB[cur][(row * 8 + (o ^ (row & 7))) * 8];
            }
        }
#pragma unroll
        for (int s2 = 0; s2 < 2; s2++)
#pragma unroll
            for (int m = 0; m < 4; m++)
#pragma unroll
                for (int n = 0; n < 2; n++)
                    acc[m][n] = __builtin_amdgcn_mfma_f32_16x16x32_bf16(
                        af[s2][m], bfr[s2][n], acc[m][n], 0, 0, 0);

        __builtin_amdgcn_sched_barrier(0);   // ds_reads consumed before barrier
        __builtin_amdgcn_s_barrier();        // safe to overwrite buf[cur] next iter
        cur ^= 1;
    }
#undef STAGE

    // C/D layout: col = lane&15, row = (lane>>4)*4 + q
#pragma unroll
    for (int m = 0; m < 4; m++) {
        int row0 = bm + wr + m * 16 + (lane >> 4) * 4;
#pragma unroll
        for (int n = 0; n < 2; n++) {
            int col = bn + wc + n * 16 + laneRow;
#pragma unroll
            for (int q = 0; q < 4; q++)
                sim[(size_t)(row0 + q) * Spad + col] = acc[m][n][q];
        }
    }
}

// -------- kernel 4: wave-per-row loss -> row_loss[s] (no atomics) --------
// float4 row reads + byte labels read as packed uint; pad label = 0xFF.
__global__ __launch_bounds__(256) void loss_kernel(
    const float* __restrict__ sim, const int* __restrict__ labels_sel,
    const int* __restrict__ meta, float* __restrict__ row_loss)
{
    int S = meta[0];
    if (blockIdx.x * 4 >= S) return;
    int Spad = (S + 127) & ~127;
    int tid = threadIdx.x;
    __shared__ unsigned char slbl[8192];
    for (int j = tid; j < Spad; j += 256)
        slbl[j] = (j < S) ? (unsigned char)labels_sel[j] : 0xFF;
    __syncthreads();

    int lane = tid & 63;
    int s = blockIdx.x * 4 + (tid >> 6);
    if (s >= S) return;

    const float4* rowv = (const float4*)(sim + (size_t)s * Spad);
    const unsigned* lblv = (const unsigned*)slbl;
    const float ONE_ME = 1.0f - 1e-5f;
    int lbl = slbl[s];
    int nv = Spad >> 2;

    // pass 1: count, min over positives (<1-eps), max over negatives
    int cnt = 0;
    float minp = INFINITY, maxn = -INFINITY;
    for (int j4 = lane; j4 < nv; j4 += 64) {
        float4 v = rowv[j4];
        unsigned lw = lblv[j4];
#pragma unroll
        for (int e = 0; e < 4; e++) {
            int j = (j4 << 2) + e;
            float sv = (&v.x)[e];
            if (j == s) sv = 1.0f;
            int lb = (lw >> (8 * e)) & 0xFF;
            if (lb == lbl) {
                cnt++;
                if (sv < ONE_ME) minp = fminf(minp, sv);
            } else if (lb != 0xFF) {
                maxn = fmaxf(maxn, sv);
            }
        }
    }
    for (int o = 32; o; o >>= 1) {
        cnt += __shfl_down(cnt, o);
        minp = fminf(minp, __shfl_down(minp, o));
        maxn = fmaxf(maxn, __shfl_down(maxn, o));
    }
    cnt  = __shfl(cnt, 0);
    minp = __shfl(minp, 0);
    maxn = __shfl(maxn, 0);

    float rl = 0.f;
    if (cnt > 1 && minp < 3e38f && maxn > -3e38f) {
        // pass 2: hard-pair exp sums (row L2-hot from pass 1)
        float psum = 0.f, nsum = 0.f;
        for (int j4 = lane; j4 < nv; j4 += 64) {
            float4 v = rowv[j4];
            unsigned lw = lblv[j4];
#pragma unroll
            for (int e = 0; e < 4; e++) {
                int j = (j4 << 2) + e;
                float sv = (&v.x)[e];
                if (j == s) sv = 1.0f;
                int lb = (lw >> (8 * e)) & 0xFF;
                if (lb == lbl) {
                    if (sv < ONE_ME && sv - 0.1f < maxn)
                        psum += __expf(-2.0f * (sv - 0.5f));
                } else if (lb != 0xFF) {
                    if (sv + 0.1f > minp)
                        nsum += __expf(40.0f * (sv - 0.5f));
                }
            }
        }
        for (int o = 32; o; o >>= 1) {
            psum += __shfl_down(psum, o);
            nsum += __shfl_down(nsum, o);
        }
        if (psum > 0.f && nsum > 0.f)
            rl = log1pf(psum) * 0.5f + log1pf(nsum) * 0.025f;
    }
    if (lane == 0) row_loss[s] = rl;
}

// -------- kernel 5: final reduction of row_loss --------
__global__ __launch_bounds__(256) void reduce_kernel(
    const float* __restrict__ row_loss, const int* __restrict__ meta,
    float* out, float invB)
{
    int S = meta[0];
    float sum = 0.f;
    for (int j = threadIdx.x; j < S; j += 256) sum += row_loss[j];
    for (int o = 32; o; o >>= 1) sum += __shfl_down(sum, o);
    __shared__ float sm[4];
    if ((threadIdx.x & 63) == 0) sm[threadIdx.x >> 6] = sum;
    __syncthreads();
    if (threadIdx.x == 0) out[0] = (sm[0] + sm[1] + sm[2] + sm[3]) * invB;
}

extern "C" void kernel_launch(void* const* d_in, const int* in_sizes, int n_in,
                              void* d_out, int out_size, void* d_ws, size_t ws_size,
                              hipStream_t stream)
{
    const float* feats    = (const float*)d_in[0];
    const void*  labels   = d_in[1];
    const float* score    = (const float*)d_in[2];
    const int*   type_idx = (const int*)d_in[3];

    int B = in_sizes[1];           // 8192
    int D = in_sizes[0] / B;       // 1024

    char* ws = (char*)d_ws;
    int*   meta       = (int*)  (ws + OFF_META);
    int*   idx_sel    = (int*)  (ws + OFF_IDXSEL);
    int*   labels_sel = (int*)  (ws + OFF_LBLSEL);
    float* row_loss   = (float*)(ws + OFF_RLOSS);
    unsigned short* fsel = (unsigned short*)(ws + OFF_FSEL);
    float* sim        = (float*)(ws + OFF_FSEL + (size_t)B * D * 2);
    float* out        = (float*)d_out;

    (void)hipMemsetAsync(meta, 0, 16, stream);

    select_kernel<<<(B + 255) / 256, 256, 0, stream>>>(score, type_idx, labels,
                                                       idx_sel, labels_sel, meta, B);
    gather_kernel<<<B / 4, 256, 0, stream>>>(feats, idx_sel, meta, fsel, D);
    dim3 g(B / 128, B / 128);
    simgemm_kernel<<<g, 512, 0, stream>>>(fsel, meta, sim, D);
    loss_kernel<<<B / 4, 256, 0, stream>>>(sim, labels_sel, meta, row_loss);
    reduce_kernel<<<1, 256, 0, stream>>>(row_loss, meta, out, 1.0f / (float)B);
}